// Round 5
// baseline (251.540 us; speedup 1.0000x reference)
//
#include <hip/hip_runtime.h>

// ---------------- constants (match reference) ----------------
// B,H,W,F,D = 8,126,126,64,32 ; grid fields are (8,128,128,32)
#define NITER 20
#define OUTER 3

constexpr double DXd  = 2.0 / 9.0;     // 2/(B+1)
constexpr double DYd  = 2.0 / 127.0;   // 2/(H+1)
constexpr double DX2d = DXd * DXd;
constexpr double DY2d = DYd * DYd;
constexpr double DENd = 2.0 * (DX2d + DY2d);

constexpr float K1     = (float)(DY2d / DENd);          // * (E+W)
constexpr float K2     = (float)(DX2d / DENd);          // * (N+S)
constexpr float CC     = (float)(DX2d * DY2d / DENd);   // c coefficient
constexpr float INV2DX = (float)(1.0 / (2.0 * DXd));
constexpr float INV2DY = (float)(1.0 / (2.0 * DYd));
constexpr float INVDT  = (float)(1.0 / 0.1);
constexpr float DTDX   = (float)(0.1 / DXd);
constexpr float DTDY   = (float)(0.1 / DYd);
constexpr float PGX    = (float)(0.1 / (2.0 * 1.0 * DXd)); // DT/(2 RHO DX)
constexpr float PGY    = (float)(0.1 / (2.0 * 1.0 * DYd));
constexpr float A1     = (float)(0.1 / DX2d);            // DT/DX2
constexpr float A2     = (float)(0.1 / DY2d);            // DT/DY2
constexpr float NUf    = 0.1f;
constexpr float FDT    = 0.1f;                           // FRC*DT

__device__ __forceinline__ float bperm(int srcByte, float v) {
    return __int_as_float(__builtin_amdgcn_ds_bpermute(srcByte, __float_as_int(v)));
}

// ---------------- kernel 1: p0 = einsum(pad(x), w) + b_lin, planar [b][d][128][128]
__global__ __launch_bounds__(256) void einsum_kernel(
    const float* __restrict__ x, const float* __restrict__ w,
    const float* __restrict__ bl, float* __restrict__ p0)
{
    int id = blockIdx.x * 256 + threadIdx.x;
    int c = id & 127, r = (id >> 7) & 127, b = id >> 14;
    float acc[32];
#pragma unroll
    for (int d = 0; d < 32; ++d) acc[d] = bl[d];
    if (r >= 1 && r <= 126 && c >= 1 && c <= 126) {
        const float* xp = x + (((size_t)(b * 126 + (r - 1))) * 126 + (c - 1)) * 64;
#pragma unroll
        for (int f = 0; f < 64; f += 4) {
            float4 xv = *(const float4*)(xp + f);
#pragma unroll
            for (int d = 0; d < 32; ++d) {
                acc[d] += xv.x * w[d * 64 + f] + xv.y * w[d * 64 + f + 1]
                        + xv.z * w[d * 64 + f + 2] + xv.w * w[d * 64 + f + 3];
            }
        }
    }
    float* op = p0 + ((size_t)b * 32) * 16384 + r * 128 + c;
#pragma unroll
    for (int d = 0; d < 32; ++d) op[(size_t)d * 16384] = acc[d];
}

// ---------------- kernel 2: the full 3-outer-iteration simulation ----------------
// one workgroup per (b,d) plane; 512 threads = 32 tx (4 cols each) x 16 ty (8 rows each).
//
// k=2 TEMPORAL BLOCKING of the Jacobi loop (Round-5): two Jacobi iterations per
// barrier. Seams carry 2 rows per side (slots {0:row0, 1:row1, 2:row6, 3:row7}).
// Per phase: step A computes iteration t on extended rows -1..8 (halo rows from
// LDS seams), BCs (A(row0):=A(row1) at ty0, A(127):=A(126) at ty15) applied
// in-register, then step B computes iteration t+1 on rows 0..7 from A. 10 phases
// x 1 barrier vs 20 x 1 before. cb lives in LDS (sCB) freeing registers; the
// old0/nrow snapshot copies vanish (B reads only A registers).
//
// LDS (128 KiB): sP[2][16][4][128] p-seam ping-pong (64K) + sCB[16][8][128] (64K).
// u,v seam exchange time-multiplexes the free sP buffer (buf1) around
// build_b/velocity, as validated in R1-R3. 128K LDS -> 1 WG/CU (structural
// anyway: grid 256 = #CUs) -> 2 waves/EU regalloc target -> 256-VGPR budget,
// killing the residual spill seen in R4 (19 MB WRITE_SIZE).
//
// Buffer protocol per outer (parity-stable):
//   entry: p seams in buf0, u,v seams in buf1.
//   build_b: reads buf1 halos, writes sCB. barrier.
//   10 phases: ph even reads buf0 writes buf1; ph odd reads buf1 writes buf0.
//              -> final p seams land in buf0.
//   velocity: publish cur u,v seams -> buf1; barrier; read u,v halos (buf1) and
//             p halos (buf0); barrier; compute; publish NEW u,v seams -> buf1;
//             barrier.  (skipped after last outer: output is p only)
__global__ __launch_bounds__(512, 2) void sim_kernel(
    const float* __restrict__ u0, const float* __restrict__ v0,
    const float* __restrict__ p0ws, const float* __restrict__ x,
    const float* __restrict__ w, const float* __restrict__ bl,
    float* __restrict__ out, int use_ws)
{
    __shared__ float sP[2][16][4][128];   // 64 KiB: p seams (and u,v seams in buf1 around velocity)
    __shared__ float sCB[16][8][128];     // 64 KiB: cb = CC*b, all rows

    const int tid = threadIdx.x;
    const int tx = tid & 31, ty = tid >> 5;
    const int c0 = tx << 2, r0 = ty << 3;
    const int lane = tid & 63;
    const int srcL = (((lane & 32) | ((lane + 31) & 31)) << 2); // lane of tx-1 (periodic)
    const int srcR = (((lane & 32) | ((lane + 1) & 31)) << 2);  // lane of tx+1
    const int bb = blockIdx.x & 7;   // batch
    const int d  = blockIdx.x >> 3;  // channel

    float pC[8][4], uC[8][4], vC[8][4];

    // ---- load u, v (strided channel reads) ----
#pragma unroll
    for (int r = 0; r < 8; ++r) {
        const size_t base = ((size_t)((bb * 128 + (r0 + r)) * 128 + c0)) * 32 + d;
#pragma unroll
        for (int c = 0; c < 4; ++c) {
            uC[r][c] = u0[base + (size_t)c * 32];
            vC[r][c] = v0[base + (size_t)c * 32];
        }
    }

    // ---- initial p ----
    if (use_ws) {
        const float* pp = p0ws + ((size_t)(bb * 32 + d)) * 16384;
#pragma unroll
        for (int r = 0; r < 8; ++r) {
            float4 t = *(const float4*)(pp + (r0 + r) * 128 + c0);
            pC[r][0] = t.x; pC[r][1] = t.y; pC[r][2] = t.z; pC[r][3] = t.w;
        }
    } else {
        const float blv = bl[d];
#pragma unroll
        for (int r = 0; r < 8; ++r) {
            const int gr = r0 + r;
#pragma unroll
            for (int c = 0; c < 4; ++c) {
                const int gc = c0 + c;
                float acc = blv;
                if (gr >= 1 && gr <= 126 && gc >= 1 && gc <= 126) {
                    const float* xp = x + (((size_t)(bb * 126 + (gr - 1))) * 126 + (gc - 1)) * 64;
                    for (int f = 0; f < 64; f += 4) {
                        float4 xv = *(const float4*)(xp + f);
                        acc += xv.x * w[d * 64 + f] + xv.y * w[d * 64 + f + 1]
                             + xv.z * w[d * 64 + f + 2] + xv.w * w[d * 64 + f + 3];
                    }
                }
                pC[r][c] = acc;
            }
        }
    }

    const int tyN = (ty > 0) ? ty - 1 : 0;    // clamped: garbage rows masked by BC overwrite
    const int tyS = (ty < 15) ? ty + 1 : 15;

    // ---- initial seam publish: p -> buf0 {r0,r1,r6,r7}, u,v -> buf1 {u0,u7,v0,v7} ----
    *(float4*)&sP[0][ty][0][c0] = make_float4(pC[0][0], pC[0][1], pC[0][2], pC[0][3]);
    *(float4*)&sP[0][ty][1][c0] = make_float4(pC[1][0], pC[1][1], pC[1][2], pC[1][3]);
    *(float4*)&sP[0][ty][2][c0] = make_float4(pC[6][0], pC[6][1], pC[6][2], pC[6][3]);
    *(float4*)&sP[0][ty][3][c0] = make_float4(pC[7][0], pC[7][1], pC[7][2], pC[7][3]);
    *(float4*)&sP[1][ty][0][c0] = make_float4(uC[0][0], uC[0][1], uC[0][2], uC[0][3]);
    *(float4*)&sP[1][ty][1][c0] = make_float4(uC[7][0], uC[7][1], uC[7][2], uC[7][3]);
    *(float4*)&sP[1][ty][2][c0] = make_float4(vC[0][0], vC[0][1], vC[0][2], vC[0][3]);
    *(float4*)&sP[1][ty][3][c0] = make_float4(vC[7][0], vC[7][1], vC[7][2], vC[7][3]);
    __syncthreads();

    for (int outer = 0; outer < OUTER; ++outer) {
        // ================= build_b -> sCB = CC * b =================
        {
            float4 uN4 = *(const float4*)&sP[1][tyN][1][c0];  // u row -1
            float4 uS4 = *(const float4*)&sP[1][tyS][0][c0];  // u row +8
            float4 vN4 = *(const float4*)&sP[1][tyN][3][c0];
            float4 vS4 = *(const float4*)&sP[1][tyS][2][c0];
            float uNh[4] = {uN4.x, uN4.y, uN4.z, uN4.w};
            float uSh[4] = {uS4.x, uS4.y, uS4.z, uS4.w};
            float vNh[4] = {vN4.x, vN4.y, vN4.z, vN4.w};
            float vSh[4] = {vS4.x, vS4.y, vS4.z, vS4.w};
#pragma unroll
            for (int r = 0; r < 8; ++r) {
                float uWh = bperm(srcL, uC[r][3]);
                float uEh = bperm(srcR, uC[r][0]);
                float vWh = bperm(srcL, vC[r][3]);
                float vEh = bperm(srcR, vC[r][0]);
                float cbr[4];
#pragma unroll
                for (int c = 0; c < 4; ++c) {
                    float uE = (c < 3) ? uC[r][c + 1] : uEh;
                    float uW = (c > 0) ? uC[r][c - 1] : uWh;
                    float vE = (c < 3) ? vC[r][c + 1] : vEh;
                    float vW = (c > 0) ? vC[r][c - 1] : vWh;
                    float uN = (r > 0) ? uC[r - 1][c] : uNh[c];
                    float uS = (r < 7) ? uC[r + 1][c] : uSh[c];
                    float vN = (r > 0) ? vC[r - 1][c] : vNh[c];
                    float vS = (r < 7) ? vC[r + 1][c] : vSh[c];
                    float dudx = (uE - uW) * INV2DX;
                    float dvdy = (vS - vN) * INV2DY;
                    float dudy = (uS - uN) * INV2DY;
                    float dvdx = (vE - vW) * INV2DX;
                    float bt = (dudx + dvdy) * INVDT - dudx * dudx
                             - 2.0f * dudy * dvdx - dvdy * dvdy;   // RHO == 1
                    cbr[c] = CC * bt;   // garbage at rows 0/127: masked by p BCs
                }
                *(float4*)&sCB[ty][r][c0] = make_float4(cbr[0], cbr[1], cbr[2], cbr[3]);
            }
        }
        __syncthreads();   // sCB visible; buf1 u,v reads done before phases clobber buf1

        // ================= pressure_poisson: 10 merged (k=2) phases =================
        for (int ph = 0; ph < NITER / 2; ++ph) {
            const int rs = ph & 1;    // read buffer (0,1,0,1,...); write rs^1
            // old halo rows from LDS
            float4 om1 = *(const float4*)&sP[rs][tyN][3][c0];           // old row -1
            float  om1W = sP[rs][tyN][3][(c0 + 127) & 127];
            float  om1E = sP[rs][tyN][3][(c0 + 4) & 127];
            float4 om2 = *(const float4*)&sP[rs][tyN][2][c0];           // old row -2
            float4 op8 = *(const float4*)&sP[rs][tyS][0][c0];           // old row +8
            float  op8W = sP[rs][tyS][0][(c0 + 127) & 127];
            float  op8E = sP[rs][tyS][0][(c0 + 4) & 127];
            float4 op9 = *(const float4*)&sP[rs][tyS][1][c0];           // old row +9
            float4 cbm1 = *(const float4*)&sCB[tyN][7][c0];             // cb row -1
            float4 cbp8 = *(const float4*)&sCB[tyS][0][c0];             // cb row +8

            float am[4], ac[4], ap[4], cbCur[4];
            // ---- step A, row -1 (halo) ----
            {
                float o0 = om1W, o1 = om1.x, o2 = om1.y, o3 = om1.z, o4 = om1.w, o5 = om1E;
                am[0] = (o2 + o0) * K1 + (om2.x + pC[0][0]) * K2 - cbm1.x;
                am[1] = (o3 + o1) * K1 + (om2.y + pC[0][1]) * K2 - cbm1.y;
                am[2] = (o4 + o2) * K1 + (om2.z + pC[0][2]) * K2 - cbm1.z;
                am[3] = (o5 + o3) * K1 + (om2.w + pC[0][3]) * K2 - cbm1.w;
            }
            // ---- step A, row 0 ----
            {
                float W = bperm(srcL, pC[0][3]);
                float E = bperm(srcR, pC[0][0]);
                float4 cb0 = *(const float4*)&sCB[ty][0][c0];
                cbCur[0] = cb0.x; cbCur[1] = cb0.y; cbCur[2] = cb0.z; cbCur[3] = cb0.w;
                float om1a[4] = {om1.x, om1.y, om1.z, om1.w};
#pragma unroll
                for (int c = 0; c < 4; ++c) {
                    float E_ = (c < 3) ? pC[0][c + 1] : E;
                    float W_ = (c > 0) ? pC[0][c - 1] : W;
                    ac[c] = (E_ + W_) * K1 + (om1a[c] + pC[1][c]) * K2 - cbCur[c];
                }
            }
#pragma unroll
            for (int r = 0; r < 8; ++r) {
                float cbN[4];
                // ---- step A, row r+1 ----
                if (r < 7) {
                    float W = bperm(srcL, pC[r + 1][3]);
                    float E = bperm(srcR, pC[r + 1][0]);
                    float4 cbv = *(const float4*)&sCB[ty][r + 1][c0];
                    cbN[0] = cbv.x; cbN[1] = cbv.y; cbN[2] = cbv.z; cbN[3] = cbv.w;
                    float Sr[4];
                    if (r + 1 < 7) {
#pragma unroll
                        for (int c = 0; c < 4; ++c) Sr[c] = pC[r + 2][c];
                    } else {
                        Sr[0] = op8.x; Sr[1] = op8.y; Sr[2] = op8.z; Sr[3] = op8.w;
                    }
#pragma unroll
                    for (int c = 0; c < 4; ++c) {
                        float E_ = (c < 3) ? pC[r + 1][c + 1] : E;
                        float W_ = (c > 0) ? pC[r + 1][c - 1] : W;
                        ap[c] = (E_ + W_) * K1 + (pC[r][c] + Sr[c]) * K2 - cbN[c];
                    }
                } else {
                    // ---- step A, row +8 (halo) ----
                    float o0 = op8W, o1 = op8.x, o2 = op8.y, o3 = op8.z, o4 = op8.w, o5 = op8E;
                    cbN[0] = cbp8.x; cbN[1] = cbp8.y; cbN[2] = cbp8.z; cbN[3] = cbp8.w;
                    ap[0] = (o2 + o0) * K1 + (pC[7][0] + op9.x) * K2 - cbN[0];
                    ap[1] = (o3 + o1) * K1 + (pC[7][1] + op9.y) * K2 - cbN[1];
                    ap[2] = (o4 + o2) * K1 + (pC[7][2] + op9.z) * K2 - cbN[2];
                    ap[3] = (o5 + o3) * K1 + (pC[7][3] + op9.w) * K2 - cbN[3];
                }
                // step-A BCs (between the two in-phase iterations)
                if (r == 0 && ty == 0) {      // A(row0) := A(row1)
#pragma unroll
                    for (int c = 0; c < 4; ++c) ac[c] = ap[c];
                }
                if (r == 6 && ty == 15) {     // A(row127) := A(row126)
#pragma unroll
                    for (int c = 0; c < 4; ++c) ap[c] = ac[c];
                }
                // ---- step B, row r (overwrites pC[r]; old pC[r] no longer needed) ----
                {
                    float W = bperm(srcL, ac[3]);
                    float E = bperm(srcR, ac[0]);
#pragma unroll
                    for (int c = 0; c < 4; ++c) {
                        float E_ = (c < 3) ? ac[c + 1] : E;
                        float W_ = (c > 0) ? ac[c - 1] : W;
                        pC[r][c] = (E_ + W_) * K1 + (am[c] + ap[c]) * K2 - cbCur[c];
                    }
                }
                // rotate window
#pragma unroll
                for (int c = 0; c < 4; ++c) { am[c] = ac[c]; ac[c] = ap[c]; cbCur[c] = cbN[c]; }
            }
            // step-B BCs
            if (ty == 0) {
#pragma unroll
                for (int c = 0; c < 4; ++c) pC[0][c] = pC[1][c];
            }
            if (ty == 15) {
#pragma unroll
                for (int c = 0; c < 4; ++c) pC[7][c] = pC[6][c];
            }
            // publish new seam rows {0,1,6,7}
            *(float4*)&sP[rs ^ 1][ty][0][c0] = make_float4(pC[0][0], pC[0][1], pC[0][2], pC[0][3]);
            *(float4*)&sP[rs ^ 1][ty][1][c0] = make_float4(pC[1][0], pC[1][1], pC[1][2], pC[1][3]);
            *(float4*)&sP[rs ^ 1][ty][2][c0] = make_float4(pC[6][0], pC[6][1], pC[6][2], pC[6][3]);
            *(float4*)&sP[rs ^ 1][ty][3][c0] = make_float4(pC[7][0], pC[7][1], pC[7][2], pC[7][3]);
            __syncthreads();
        }
        // 10 phases -> final p seams sit in buf0

        // ================= velocity_step (skipped after last outer: output is p) ========
        if (outer < OUTER - 1) {
            // publish current (pre-update) u,v seams into buf1 for halo exchange
            *(float4*)&sP[1][ty][0][c0] = make_float4(uC[0][0], uC[0][1], uC[0][2], uC[0][3]);
            *(float4*)&sP[1][ty][1][c0] = make_float4(uC[7][0], uC[7][1], uC[7][2], uC[7][3]);
            *(float4*)&sP[1][ty][2][c0] = make_float4(vC[0][0], vC[0][1], vC[0][2], vC[0][3]);
            *(float4*)&sP[1][ty][3][c0] = make_float4(vC[7][0], vC[7][1], vC[7][2], vC[7][3]);
            __syncthreads();

            float4 ut4 = *(const float4*)&sP[1][tyN][1][c0];  // u row -1
            float4 us4 = *(const float4*)&sP[1][tyS][0][c0];  // u row +8
            float4 vt4 = *(const float4*)&sP[1][tyN][3][c0];
            float4 vs4 = *(const float4*)&sP[1][tyS][2][c0];
            float4 pt4 = *(const float4*)&sP[0][tyN][3][c0];  // final p row -1
            float4 pb4 = *(const float4*)&sP[0][tyS][0][c0];  // final p row +8
            float uNh[4] = {ut4.x, ut4.y, ut4.z, ut4.w};
            float uSh[4] = {us4.x, us4.y, us4.z, us4.w};
            float vNh[4] = {vt4.x, vt4.y, vt4.z, vt4.w};
            float vSh[4] = {vs4.x, vs4.y, vs4.z, vs4.w};
            float pNh[4] = {pt4.x, pt4.y, pt4.z, pt4.w};
            float pSh[4] = {pb4.x, pb4.y, pb4.z, pb4.w};
            __syncthreads();   // all halo reads done before buf1 rewrite below

            float uNrow[4], vNrow[4];
#pragma unroll
            for (int c = 0; c < 4; ++c) { uNrow[c] = uNh[c]; vNrow[c] = vNh[c]; }
#pragma unroll
            for (int r = 0; r < 8; ++r) {
                float uold[4], vold[4];  // snapshot: same-row W neighbors must be OLD
#pragma unroll
                for (int c = 0; c < 4; ++c) { uold[c] = uC[r][c]; vold[c] = vC[r][c]; }
                float uWh = bperm(srcL, uold[3]);
                float uEh = bperm(srcR, uold[0]);
                float vWh = bperm(srcL, vold[3]);
                float vEh = bperm(srcR, vold[0]);
                float pWh = bperm(srcL, pC[r][3]);
                float pEh = bperm(srcR, pC[r][0]);
#pragma unroll
                for (int c = 0; c < 4; ++c) {
                    float uc = uold[c], vc = vold[c];
                    float uE = (c < 3) ? uold[c + 1] : uEh;
                    float uW = (c > 0) ? uold[c - 1] : uWh;
                    float vE = (c < 3) ? vold[c + 1] : vEh;
                    float vW = (c > 0) ? vold[c - 1] : vWh;
                    float uN = uNrow[c];
                    float uS = (r < 7) ? uC[r + 1][c] : uSh[c];
                    float vN = vNrow[c];
                    float vS = (r < 7) ? vC[r + 1][c] : vSh[c];
                    float pE = (c < 3) ? pC[r][c + 1] : pEh;
                    float pW = (c > 0) ? pC[r][c - 1] : pWh;
                    float pN = (r > 0) ? pC[r - 1][c] : pNh[c];
                    float pS = (r < 7) ? pC[r + 1][c] : pSh[c];

                    float unew = uc - uc * DTDX * (uc - uW) - vc * DTDY * (uc - uN)
                               - PGX * (pE - pW)
                               + NUf * (A1 * (uE - 2.0f * uc + uW) + A2 * (uS - 2.0f * uc + uN))
                               + FDT;
                    float vnew = vc - uc * DTDX * (vc - vW) - vc * DTDY * (vc - vN)
                               - PGY * (pS - pN)
                               + NUf * (A1 * (vE - 2.0f * vc + vW) + A2 * (vS - 2.0f * vc + vN));
                    uC[r][c] = unew;
                    vC[r][c] = vnew;
                }
#pragma unroll
                for (int c = 0; c < 4; ++c) { uNrow[c] = uold[c]; vNrow[c] = vold[c]; }
            }
            // u,v row BCs: rows 0 and 127 -> 0 (also masks garbage edge computes)
            if (ty == 0) {
#pragma unroll
                for (int c = 0; c < 4; ++c) { uC[0][c] = 0.0f; vC[0][c] = 0.0f; }
            }
            if (ty == 15) {
#pragma unroll
                for (int c = 0; c < 4; ++c) { uC[7][c] = 0.0f; vC[7][c] = 0.0f; }
            }
            // publish NEW u,v seams for next outer's build_b
            *(float4*)&sP[1][ty][0][c0] = make_float4(uC[0][0], uC[0][1], uC[0][2], uC[0][3]);
            *(float4*)&sP[1][ty][1][c0] = make_float4(uC[7][0], uC[7][1], uC[7][2], uC[7][3]);
            *(float4*)&sP[1][ty][2][c0] = make_float4(vC[0][0], vC[0][1], vC[0][2], vC[0][3]);
            *(float4*)&sP[1][ty][3][c0] = make_float4(vC[7][0], vC[7][1], vC[7][2], vC[7][3]);
            __syncthreads();
        }
    }

    // ---- output: p[:, row 127, :, :]  -> out[b][col][d] ----
    if (ty == 15) {
        float* op = out + ((size_t)bb * 128 + c0) * 32 + d;
        op[0]  = pC[7][0];
        op[32] = pC[7][1];
        op[64] = pC[7][2];
        op[96] = pC[7][3];
    }
}

extern "C" void kernel_launch(void* const* d_in, const int* in_sizes, int n_in,
                              void* d_out, int out_size, void* d_ws, size_t ws_size,
                              hipStream_t stream) {
    const float* x  = (const float*)d_in[0];
    const float* u0 = (const float*)d_in[1];
    const float* v0 = (const float*)d_in[2];
    const float* w  = (const float*)d_in[3];
    const float* bl = (const float*)d_in[4];
    float* out = (float*)d_out;
    float* p0  = (float*)d_ws;

    const size_t need = (size_t)8 * 32 * 128 * 128 * sizeof(float);
    const int use_ws = (ws_size >= need) ? 1 : 0;

    if (use_ws) {
        einsum_kernel<<<512, 256, 0, stream>>>(x, w, bl, p0);
    }
    sim_kernel<<<256, 512, 0, stream>>>(u0, v0, p0, x, w, bl, out, use_ws);
}